// Round 8
// baseline (1470.339 us; speedup 1.0000x reference)
//
#include <hip/hip_runtime.h>
#include <stdint.h>

#define BATCH 4
#define NPTS 8192
#define KNN_K 16
#define GRID 16
#define NCELL (GRID * GRID * GRID)  // 4096

typedef unsigned long long u64;
typedef unsigned short u16;

// ws layout (bytes)
#define WS_IDX 0u          // u16[4*8192*16]            = 1,048,576
#define WS_LT 1048576u     // float[4*8192*192]         = 25,165,824
#define WS_CNT 26214400u   // int[4*4096]               = 65,536
#define WS_OFF 26435584u   // int[4*4096]               = 65,536
#define WS_CUR 26656768u   // int[4*4096]               = 65,536
#define WS_SP 26877952u    // float4[4*8192]            = 524,288
#define WS_GP 27402240u    // float[4*8]                = 128

__device__ __forceinline__ int cellof(float v, float o, float invs) {
  int c = (int)((v - o) * invs);
  return c < GRID - 1 ? c : GRID - 1;
}

// ---------------------------------------------------------------- K0: bbox + zero counters
__global__ __launch_bounds__(256) void k_minmax(const float4* __restrict__ xytp,
                                                float* __restrict__ gp,
                                                int* __restrict__ cnt) {
  const int b = blockIdx.x, t = threadIdx.x;
  for (int c = t; c < NCELL; c += 256) cnt[b * NCELL + c] = 0;
  const float4* pb = xytp + (b << 13);
  float mnx = INFINITY, mny = INFINITY, mnz = INFINITY;
  float mxx = -INFINITY, mxy = -INFINITY, mxz = -INFINITY;
  for (int i = t; i < NPTS; i += 256) {
    float4 p = pb[i];
    mnx = fminf(mnx, p.x); mny = fminf(mny, p.y); mnz = fminf(mnz, p.z);
    mxx = fmaxf(mxx, p.x); mxy = fmaxf(mxy, p.y); mxz = fmaxf(mxz, p.z);
  }
#pragma unroll
  for (int d = 1; d < 64; d <<= 1) {
    mnx = fminf(mnx, __shfl_xor(mnx, d)); mny = fminf(mny, __shfl_xor(mny, d));
    mnz = fminf(mnz, __shfl_xor(mnz, d)); mxx = fmaxf(mxx, __shfl_xor(mxx, d));
    mxy = fmaxf(mxy, __shfl_xor(mxy, d)); mxz = fmaxf(mxz, __shfl_xor(mxz, d));
  }
  __shared__ float red[4][6];
  const int lane = t & 63, wv = t >> 6;
  if (lane == 0) {
    red[wv][0] = mnx; red[wv][1] = mny; red[wv][2] = mnz;
    red[wv][3] = mxx; red[wv][4] = mxy; red[wv][5] = mxz;
  }
  __syncthreads();
  if (t == 0) {
    for (int w = 1; w < 4; ++w) {
      red[0][0] = fminf(red[0][0], red[w][0]);
      red[0][1] = fminf(red[0][1], red[w][1]);
      red[0][2] = fminf(red[0][2], red[w][2]);
      red[0][3] = fmaxf(red[0][3], red[w][3]);
      red[0][4] = fmaxf(red[0][4], red[w][4]);
      red[0][5] = fmaxf(red[0][5], red[w][5]);
    }
    float rmax = fmaxf(red[0][3] - red[0][0],
                       fmaxf(red[0][4] - red[0][1], red[0][5] - red[0][2]));
    float s = rmax / (float)GRID;
    float* g = gp + b * 8;
    g[0] = red[0][0]; g[1] = red[0][1]; g[2] = red[0][2];
    g[3] = s; g[4] = 1.0f / s;
  }
}

// ---------------------------------------------------------------- K2: count
__global__ __launch_bounds__(256) void k_count(const float4* __restrict__ xytp,
                                               const float* __restrict__ gp,
                                               int* __restrict__ cnt) {
  int i = blockIdx.x * 256 + threadIdx.x;
  int b = i >> 13;
  const float* g = gp + b * 8;
  float4 p = xytp[i];
  int cx = cellof(p.x, g[0], g[4]);
  int cy = cellof(p.y, g[1], g[4]);
  int cz = cellof(p.z, g[2], g[4]);
  atomicAdd(&cnt[b * NCELL + (cz * GRID + cy) * GRID + cx], 1);
}

// ---------------------------------------------------------------- K3: exclusive scan (one block per batch)
__global__ __launch_bounds__(1024) void k_scan(const int* __restrict__ cnt,
                                               int* __restrict__ offs,
                                               int* __restrict__ curs) {
  __shared__ int wsum[16];
  const int b = blockIdx.x, t = threadIdx.x;
  const int base = b * NCELL;
  const int PER = NCELL / 1024;  // 4
  const int lo = t * PER;
  int s = 0;
  for (int c = lo; c < lo + PER; ++c) s += cnt[base + c];
  const int lane = t & 63, wv = t >> 6;
  int v = s;
#pragma unroll
  for (int d = 1; d < 64; d <<= 1) {
    int u = __shfl_up(v, d);
    if (lane >= d) v += u;
  }
  if (lane == 63) wsum[wv] = v;
  __syncthreads();
  if (wv == 0 && lane < 16) {
    int x = wsum[lane];
#pragma unroll
    for (int d = 1; d < 16; d <<= 1) {
      int u = __shfl_up(x, d, 16);
      if (lane >= d) x += u;
    }
    wsum[lane] = x;
  }
  __syncthreads();
  int excl = (wv > 0 ? wsum[wv - 1] : 0) + v - s;
  for (int c = lo; c < lo + PER; ++c) {
    offs[base + c] = excl;
    curs[base + c] = excl;
    excl += cnt[base + c];
  }
}

// ---------------------------------------------------------------- K4: scatter into cell-sorted order
__global__ __launch_bounds__(256) void k_scatter(const float4* __restrict__ xytp,
                                                 const float* __restrict__ gp,
                                                 int* __restrict__ curs,
                                                 float4* __restrict__ spts) {
  int i = blockIdx.x * 256 + threadIdx.x;
  int b = i >> 13, n = i & 8191;
  const float* g = gp + b * 8;
  float4 p = xytp[i];
  int cx = cellof(p.x, g[0], g[4]);
  int cy = cellof(p.y, g[1], g[4]);
  int cz = cellof(p.z, g[2], g[4]);
  int pos = atomicAdd(&curs[b * NCELL + (cz * GRID + cy) * GRID + cx], 1);
  spts[(b << 13) + pos] = make_float4(p.x, p.y, p.z, __int_as_float(n));
}

// ---------------------------------------------------------------- K5: grid KNN query, 8-lane teams, segment-parallel
// Team = 8 consecutive lanes per query (queries in cell-sorted order).
// Each shell r is decomposed into contiguous row-segments (full rows on the
// z/y faces, single cells at x=cx±r on interior rows); segments are dealt
// round-robin to the 8 lanes, so up to 8 dependent offset-load chains are
// in flight per team (R7 had ONE).  Per-lane exact top-16 via (d2,idx)
// u64 keys (validated R1-R7 formula); partition across lanes is
// order-invariant.  Stop: team-min of lane 16th-bests <= (r*s)^2 - eps
// (each lane's 16th-best >= union 16th-best, so the min still is).
#define SCANSEG(S0, S1)                                                      \
  for (int j = (S0); j < (S1); ++j) {                                        \
    float4 A = sp[j];                                                        \
    float sqj = fmaf(A.z, A.z, fmaf(A.y, A.y, A.x * A.x));                   \
    float dot = q.x * A.x;                                                   \
    dot = fmaf(q.y, A.y, dot);                                               \
    dot = fmaf(q.z, A.z, dot);                                               \
    float d2 = (qsq + sqj) - 2.0f * dot;                                     \
    unsigned u = __float_as_uint(d2);                                        \
    u ^= (0x80000000u | (unsigned)((int)u >> 31));                           \
    u64 key = ((u64)u << 32) | (unsigned)__float_as_int(A.w);                \
    if (key < lst[15]) {                                                     \
      u64 x = key;                                                           \
      _Pragma("unroll") for (int p = 0; p < 16; ++p) {                       \
        bool sw = x < lst[p];                                                \
        u64 a = lst[p];                                                      \
        lst[p] = sw ? x : a;                                                 \
        x = sw ? a : x;                                                      \
      }                                                                      \
    }                                                                        \
  }

__global__ __launch_bounds__(256) void k_query(const float4* __restrict__ spts,
                                               const int* __restrict__ offs,
                                               const int* __restrict__ ends,
                                               const float* __restrict__ gp,
                                               u16* __restrict__ oidx) {
  __shared__ u64 kb[16 * 256];  // 32 KB: kb[(slot<<8) + qq*8 + list]
  const int tid = threadIdx.x;
  const int l = tid & 7;       // team lane
  const int qq = tid >> 3;     // query within block (0..31)
  const int qid = blockIdx.x * 32 + qq;
  const int b = qid >> 13, i = qid & 8191;
  const float4* __restrict__ sp = spts + (b << 13);
  const int* __restrict__ ob = offs + b * NCELL;
  const int* __restrict__ eb = ends + b * NCELL;
  const float* g = gp + b * 8;
  float4 q = sp[i];
  const float qsq = fmaf(q.z, q.z, fmaf(q.y, q.y, q.x * q.x));
  const int orig = __float_as_int(q.w);
  const int cx = cellof(q.x, g[0], g[4]);
  const int cy = cellof(q.y, g[1], g[4]);
  const int cz = cellof(q.z, g[2], g[4]);
  const float s = g[3];

  u64 lst[16];
#pragma unroll
  for (int p = 0; p < 16; ++p) lst[p] = ~0ULL;

  for (int r = 0; r <= GRID; ++r) {
    const int zlo = cz - r < 0 ? 0 : cz - r;
    const int zhi = cz + r > GRID - 1 ? GRID - 1 : cz + r;
    const int xlo = cx - r < 0 ? 0 : cx - r;
    const int xhi = cx + r > GRID - 1 ? GRID - 1 : cx + r;
    int seg = 0;  // identical enumeration on all 8 lanes
    for (int z2 = zlo; z2 <= zhi; ++z2) {
      const int dz = z2 - cz;
      const bool zface = (dz == -r) || (dz == r);
      const int ylo = cy - r < 0 ? 0 : cy - r;
      const int yhi = cy + r > GRID - 1 ? GRID - 1 : cy + r;
      for (int y2 = ylo; y2 <= yhi; ++y2) {
        const int dy = y2 - cy;
        const int rowb = (z2 * GRID + y2) * GRID;
        if (zface || dy == -r || dy == r) {
          if ((seg & 7) == l) {  // full row: contiguous cells xlo..xhi
            int s0 = ob[rowb + xlo], s1 = eb[rowb + xhi];
            SCANSEG(s0, s1)
          }
          ++seg;
        } else {  // interior row: only x = cx±r (r >= 1 here)
          int x2 = cx - r;
          if (x2 >= 0) {
            if ((seg & 7) == l) {
              int s0 = ob[rowb + x2], s1 = eb[rowb + x2];
              SCANSEG(s0, s1)
            }
            ++seg;
          }
          x2 = cx + r;
          if (x2 < GRID) {
            if ((seg & 7) == l) {
              int s0 = ob[rowb + x2], s1 = eb[rowb + x2];
              SCANSEG(s0, s1)
            }
            ++seg;
          }
        }
      }
    }
    // team stop check (lanes 8-aligned: xor 1,2,4 stays in-team)
    float worst;
    if (lst[15] == ~0ULL) {
      worst = INFINITY;
    } else {
      unsigned v = (unsigned)(lst[15] >> 32);
      unsigned uo = (v & 0x80000000u) ? (v ^ 0x80000000u) : ~v;
      worst = __uint_as_float(uo);
    }
    worst = fminf(worst, __shfl_xor(worst, 1));
    worst = fminf(worst, __shfl_xor(worst, 2));
    worst = fminf(worst, __shfl_xor(worst, 4));
    float rs = (float)r * s;
    if (worst <= fmaf(rs, rs, -1e-4f)) break;
  }

  // ---- merge 8 sorted lists per query (3 stages) ----
#pragma unroll
  for (int p = 0; p < 16; ++p) kb[(p << 8) + tid] = lst[p];
  __syncthreads();

  const int base = qq << 3;
  u64 rb[16];
  {  // stage 1: lanes 0..3 merge (base+2l, base+2l+1) -> base+2l
    const bool act = (l < 4);
    if (act) {
      const int la = base + 2 * l, lb = la + 1;
      int pa = 0, pb = 0;
      u64 ka = kb[la], kv = kb[lb];
#pragma unroll
      for (int k = 0; k < 16; ++k) {
        bool ta = ka < kv;
        rb[k] = ta ? ka : kv;
        if (ta) {
          ++pa;
          ka = (pa < 16) ? kb[(pa << 8) + la] : ~0ULL;
        } else {
          ++pb;
          kv = (pb < 16) ? kb[(pb << 8) + lb] : ~0ULL;
        }
      }
    }
    __syncthreads();
    if (act) {
#pragma unroll
      for (int p = 0; p < 16; ++p) kb[(p << 8) + base + 2 * l] = rb[p];
    }
    __syncthreads();
  }
  {  // stage 2: lanes 0..1 merge (base+4l, base+4l+2) -> base+4l
    const bool act = (l < 2);
    if (act) {
      const int la = base + 4 * l, lb = la + 2;
      int pa = 0, pb = 0;
      u64 ka = kb[la], kv = kb[lb];
#pragma unroll
      for (int k = 0; k < 16; ++k) {
        bool ta = ka < kv;
        rb[k] = ta ? ka : kv;
        if (ta) {
          ++pa;
          ka = (pa < 16) ? kb[(pa << 8) + la] : ~0ULL;
        } else {
          ++pb;
          kv = (pb < 16) ? kb[(pb << 8) + lb] : ~0ULL;
        }
      }
    }
    __syncthreads();
    if (act) {
#pragma unroll
      for (int p = 0; p < 16; ++p) kb[(p << 8) + base + 4 * l] = rb[p];
    }
    __syncthreads();
  }
  if (l == 0) {  // stage 3: merge (base, base+4) -> output
    const int la = base, lb = base + 4;
    int pa = 0, pb = 0;
    u64 ka = kb[la], kv = kb[lb];
    unsigned pk[8];
#pragma unroll
    for (int k = 0; k < 16; ++k) {
      bool ta = ka < kv;
      u64 sel = ta ? ka : kv;
      unsigned id16 = (unsigned)(sel & 0xFFFFull);
      if (k & 1)
        pk[k >> 1] |= id16 << 16;
      else
        pk[k >> 1] = id16;
      if (ta) {
        ++pa;
        ka = (pa < 16) ? kb[(pa << 8) + la] : ~0ULL;
      } else {
        ++pb;
        kv = (pb < 16) ? kb[(pb << 8) + lb] : ~0ULL;
      }
    }
    unsigned* od = (unsigned*)(oidx + (((size_t)(b << 13) + orig) << 4));
#pragma unroll
    for (int k = 0; k < 8; ++k) od[k] = pk[k];
  }
}

// ---------------------------------------------------------------- K6: lt = feat @ lt_w + lt_b
__global__ __launch_bounds__(256) void k_lt(const float* __restrict__ feat,
                                            const float* __restrict__ ltw,
                                            const float* __restrict__ ltb,
                                            float* __restrict__ lt) {
  __shared__ float sw[64][196];
  __shared__ float sf[32][68];
  const int tid = threadIdx.x;
  const int r0 = blockIdx.x * 32;
#pragma unroll
  for (int i = 0; i < 12; ++i) {
    int v = tid + i * 256;
    float4 w4 = ((const float4*)ltw)[v];
    int row = (v * 4) / 192, col = (v * 4) % 192;
    *(float4*)&sw[row][col] = w4;
  }
#pragma unroll
  for (int i = 0; i < 2; ++i) {
    int v = tid + i * 256;
    int row = v >> 4, c4 = v & 15;
    float4 f4 = ((const float4*)(feat + (size_t)(r0 + row) * 64))[c4];
    *(float4*)&sf[row][c4 * 4] = f4;
  }
  __syncthreads();
  const int r = tid >> 3;
  const int c0 = (tid & 7) * 24;
  float acc[24];
#pragma unroll
  for (int ll = 0; ll < 24; ++ll) acc[ll] = ltb[c0 + ll];
#pragma unroll 4
  for (int j = 0; j < 64; ++j) {
    float f = sf[r][j];
#pragma unroll
    for (int l4 = 0; l4 < 6; ++l4) {
      float4 w4 = *(const float4*)&sw[j][c0 + l4 * 4];
      acc[l4 * 4 + 0] = fmaf(f, w4.x, acc[l4 * 4 + 0]);
      acc[l4 * 4 + 1] = fmaf(f, w4.y, acc[l4 * 4 + 1]);
      acc[l4 * 4 + 2] = fmaf(f, w4.z, acc[l4 * 4 + 2]);
      acc[l4 * 4 + 3] = fmaf(f, w4.w, acc[l4 * 4 + 3]);
    }
  }
  float* orow = lt + (size_t)(r0 + r) * 192 + c0;
#pragma unroll
  for (int l4 = 0; l4 < 6; ++l4)
    *(float4*)&orow[l4 * 4] = make_float4(acc[l4 * 4], acc[l4 * 4 + 1],
                                          acc[l4 * 4 + 2], acc[l4 * 4 + 3]);
}

// ---------------------------------------------------------------- K7: main
__global__ __launch_bounds__(256) void k_main(
    const float4* __restrict__ xytp, const float* __restrict__ lt,
    const u16* __restrict__ knn, const float* __restrict__ pe_w1,
    const float* __restrict__ pe_b1, const float* __restrict__ pe_w2,
    const float* __restrict__ pe_b2, const float* __restrict__ ln_g,
    const float* __restrict__ ln_b, float* __restrict__ out) {
  __shared__ float s_h[4][16][64];
  const int lane = threadIdx.x & 63;
  const int wave = threadIdx.x >> 6;
  const int pid = __builtin_amdgcn_readfirstlane(blockIdx.x * 4 + wave);
  const int b = pid >> 13;
  const int n = pid & 8191;

  float w1c[4];
#pragma unroll
  for (int d = 0; d < 4; ++d) w1c[d] = pe_w1[d * 64 + lane];
  const float b1c = pe_b1[lane];
  float w2c[64];
#pragma unroll
  for (int j = 0; j < 64; ++j) w2c[j] = pe_w2[j * 64 + lane];
  const float b2c = pe_b2[lane];
  const float gc = ln_g[lane], bc = ln_b[lane];

  int nb[16];
#pragma unroll
  for (int k = 0; k < 16; ++k) nb[k] = knn[pid * 16 + k];

  const float* __restrict__ ltb = lt + (size_t)(b << 13) * 192;
  float psi[16], alp[16];
#pragma unroll
  for (int k = 0; k < 16; ++k) {
    const float* row = ltb + (size_t)nb[k] * 192;
    psi[k] = row[64 + lane];
    alp[k] = row[128 + lane];
  }
  const float vc = ltb[(size_t)n * 192 + lane];

  const float4 qv = xytp[(b << 13) + n];
#pragma unroll
  for (int k = 0; k < 16; ++k) {
    float4 g = xytp[(b << 13) + nb[k]];
    float r0 = qv.x - g.x, r1 = qv.y - g.y, r2 = qv.z - g.z, r3 = qv.w - g.w;
    float h = fmaf(r3, w1c[3],
                   fmaf(r2, w1c[2], fmaf(r1, w1c[1], fmaf(r0, w1c[0], b1c))));
    s_h[wave][k][lane] = fmaxf(h, 0.0f);
  }
  __syncthreads();

  float pre[16], apd[16];
#pragma unroll
  for (int k = 0; k < 16; ++k) {
    float acc = b2c;
#pragma unroll
    for (int j4 = 0; j4 < 16; ++j4) {
      float4 h4 = *(const float4*)&s_h[wave][k][j4 * 4];
      acc = fmaf(h4.x, w2c[j4 * 4 + 0], acc);
      acc = fmaf(h4.y, w2c[j4 * 4 + 1], acc);
      acc = fmaf(h4.z, w2c[j4 * 4 + 2], acc);
      acc = fmaf(h4.w, w2c[j4 * 4 + 3], acc);
    }
    pre[k] = (vc - psi[k]) + acc;
    apd[k] = alp[k] + acc;
  }

  float xk[16], m = -INFINITY;
#pragma unroll
  for (int k = 0; k < 16; ++k) {
    float s = pre[k], ss = pre[k] * pre[k];
#pragma unroll
    for (int d = 1; d < 64; d <<= 1) {
      s += __shfl_xor(s, d);
      ss += __shfl_xor(ss, d);
    }
    float mu = s * 0.015625f;
    float var = fmaf(ss, 0.015625f, -mu * mu);
    float inv = 1.0f / sqrtf(var + 1e-5f);
    float lnv = fmaf((pre[k] - mu) * inv, gc, bc);
    xk[k] = lnv * 0.125f;
    m = fmaxf(m, xk[k]);
  }
  float se = 0.f, acc = 0.f;
#pragma unroll
  for (int k = 0; k < 16; ++k) {
    float e = __expf(xk[k] - m);
    se += e;
    acc = fmaf(e, apd[k], acc);
  }
  out[(size_t)pid * 64 + lane] = acc / se;
}

// ---------------------------------------------------------------- launch
extern "C" void kernel_launch(void* const* d_in, const int* in_sizes, int n_in,
                              void* d_out, int out_size, void* d_ws,
                              size_t ws_size, hipStream_t stream) {
  const float4* xytp = (const float4*)d_in[0];
  const float* features = (const float*)d_in[1];
  const float* pe_w1 = (const float*)d_in[2];
  const float* pe_b1 = (const float*)d_in[3];
  const float* pe_w2 = (const float*)d_in[4];
  const float* pe_b2 = (const float*)d_in[5];
  const float* lt_w = (const float*)d_in[6];
  const float* lt_b = (const float*)d_in[7];
  const float* ln_g = (const float*)d_in[8];
  const float* ln_b = (const float*)d_in[9];
  float* out = (float*)d_out;

  char* ws = (char*)d_ws;
  u16* idxbuf = (u16*)(ws + WS_IDX);
  float* lt = (float*)(ws + WS_LT);
  int* cnt = (int*)(ws + WS_CNT);
  int* offs = (int*)(ws + WS_OFF);
  int* curs = (int*)(ws + WS_CUR);
  float4* spts = (float4*)(ws + WS_SP);
  float* gp = (float*)(ws + WS_GP);

  k_minmax<<<BATCH, 256, 0, stream>>>(xytp, gp, cnt);
  k_count<<<(BATCH * NPTS) / 256, 256, 0, stream>>>(xytp, gp, cnt);
  k_scan<<<BATCH, 1024, 0, stream>>>(cnt, offs, curs);
  k_scatter<<<(BATCH * NPTS) / 256, 256, 0, stream>>>(xytp, gp, curs, spts);
  k_query<<<(BATCH * NPTS * 8) / 256, 256, 0, stream>>>(spts, offs, curs, gp,
                                                        idxbuf);
  k_lt<<<(BATCH * NPTS) / 32, 256, 0, stream>>>(features, lt_w, lt_b, lt);
  k_main<<<(BATCH * NPTS) / 4, 256, 0, stream>>>(xytp, lt, idxbuf, pe_w1,
                                                 pe_b1, pe_w2, pe_b2, ln_g,
                                                 ln_b, out);
}

// Round 9
// 656.508 us; speedup vs baseline: 2.2396x; 2.2396x over previous
//
#include <hip/hip_runtime.h>
#include <stdint.h>

#define BATCH 4
#define NPTS 8192
#define KNN_K 16
#define GRID 24
#define NCELL (GRID * GRID * GRID)  // 13824

typedef unsigned long long u64;
typedef unsigned short u16;

// ws layout (bytes)
#define WS_IDX 0u          // u16[4*8192*16]            = 1,048,576
#define WS_LT 1048576u     // float[4*8192*192]         = 25,165,824
#define WS_CNT 26214400u   // int[4*13824]              = 221,184
#define WS_OFF 26435584u   // int[4*13824]              = 221,184
#define WS_CUR 26656768u   // int[4*13824]              = 221,184
#define WS_SP 26877952u    // float4[4*8192]            = 524,288
#define WS_GP 27402240u    // float[4*8]                = 128

__device__ __forceinline__ int cellof(float v, float o, float invs) {
  int c = (int)((v - o) * invs);
  return c < GRID - 1 ? c : GRID - 1;
}

// ---------------------------------------------------------------- K0: bbox + zero counters
__global__ __launch_bounds__(256) void k_minmax(const float4* __restrict__ xytp,
                                                float* __restrict__ gp,
                                                int* __restrict__ cnt) {
  const int b = blockIdx.x, t = threadIdx.x;
  for (int c = t; c < NCELL; c += 256) cnt[b * NCELL + c] = 0;
  const float4* pb = xytp + (b << 13);
  float mnx = INFINITY, mny = INFINITY, mnz = INFINITY;
  float mxx = -INFINITY, mxy = -INFINITY, mxz = -INFINITY;
  for (int i = t; i < NPTS; i += 256) {
    float4 p = pb[i];
    mnx = fminf(mnx, p.x); mny = fminf(mny, p.y); mnz = fminf(mnz, p.z);
    mxx = fmaxf(mxx, p.x); mxy = fmaxf(mxy, p.y); mxz = fmaxf(mxz, p.z);
  }
#pragma unroll
  for (int d = 1; d < 64; d <<= 1) {
    mnx = fminf(mnx, __shfl_xor(mnx, d)); mny = fminf(mny, __shfl_xor(mny, d));
    mnz = fminf(mnz, __shfl_xor(mnz, d)); mxx = fmaxf(mxx, __shfl_xor(mxx, d));
    mxy = fmaxf(mxy, __shfl_xor(mxy, d)); mxz = fmaxf(mxz, __shfl_xor(mxz, d));
  }
  __shared__ float red[4][6];
  const int lane = t & 63, wv = t >> 6;
  if (lane == 0) {
    red[wv][0] = mnx; red[wv][1] = mny; red[wv][2] = mnz;
    red[wv][3] = mxx; red[wv][4] = mxy; red[wv][5] = mxz;
  }
  __syncthreads();
  if (t == 0) {
    for (int w = 1; w < 4; ++w) {
      red[0][0] = fminf(red[0][0], red[w][0]);
      red[0][1] = fminf(red[0][1], red[w][1]);
      red[0][2] = fminf(red[0][2], red[w][2]);
      red[0][3] = fmaxf(red[0][3], red[w][3]);
      red[0][4] = fmaxf(red[0][4], red[w][4]);
      red[0][5] = fmaxf(red[0][5], red[w][5]);
    }
    float rmax = fmaxf(red[0][3] - red[0][0],
                       fmaxf(red[0][4] - red[0][1], red[0][5] - red[0][2]));
    float s = rmax / (float)GRID;
    float* g = gp + b * 8;
    g[0] = red[0][0]; g[1] = red[0][1]; g[2] = red[0][2];
    g[3] = s; g[4] = 1.0f / s;
  }
}

// ---------------------------------------------------------------- K2: count
__global__ __launch_bounds__(256) void k_count(const float4* __restrict__ xytp,
                                               const float* __restrict__ gp,
                                               int* __restrict__ cnt) {
  int i = blockIdx.x * 256 + threadIdx.x;
  int b = i >> 13;
  const float* g = gp + b * 8;
  float4 p = xytp[i];
  int cx = cellof(p.x, g[0], g[4]);
  int cy = cellof(p.y, g[1], g[4]);
  int cz = cellof(p.z, g[2], g[4]);
  atomicAdd(&cnt[b * NCELL + (cz * GRID + cy) * GRID + cx], 1);
}

// ---------------------------------------------------------------- K3: exclusive scan (one block per batch)
__global__ __launch_bounds__(1024) void k_scan(const int* __restrict__ cnt,
                                               int* __restrict__ offs,
                                               int* __restrict__ curs) {
  __shared__ int wsum[16];
  const int b = blockIdx.x, t = threadIdx.x;
  const int base = b * NCELL;
  const int lo = t * 14;
  const int hi = lo + 14 < NCELL ? lo + 14 : NCELL;
  int s = 0;
  for (int c = lo; c < hi; ++c) s += cnt[base + c];
  const int lane = t & 63, wv = t >> 6;
  int v = s;
#pragma unroll
  for (int d = 1; d < 64; d <<= 1) {
    int u = __shfl_up(v, d);
    if (lane >= d) v += u;
  }
  if (lane == 63) wsum[wv] = v;
  __syncthreads();
  if (wv == 0 && lane < 16) {
    int x = wsum[lane];
#pragma unroll
    for (int d = 1; d < 16; d <<= 1) {
      int u = __shfl_up(x, d, 16);
      if (lane >= d) x += u;
    }
    wsum[lane] = x;
  }
  __syncthreads();
  int excl = (wv > 0 ? wsum[wv - 1] : 0) + v - s;
  for (int c = lo; c < hi; ++c) {
    offs[base + c] = excl;
    curs[base + c] = excl;
    excl += cnt[base + c];
  }
}

// ---------------------------------------------------------------- K4: scatter into cell-sorted order
__global__ __launch_bounds__(256) void k_scatter(const float4* __restrict__ xytp,
                                                 const float* __restrict__ gp,
                                                 int* __restrict__ curs,
                                                 float4* __restrict__ spts) {
  int i = blockIdx.x * 256 + threadIdx.x;
  int b = i >> 13, n = i & 8191;
  const float* g = gp + b * 8;
  float4 p = xytp[i];
  int cx = cellof(p.x, g[0], g[4]);
  int cy = cellof(p.y, g[1], g[4]);
  int cz = cellof(p.z, g[2], g[4]);
  int pos = atomicAdd(&curs[b * NCELL + (cz * GRID + cy) * GRID + cx], 1);
  spts[(b << 13) + pos] = make_float4(p.x, p.y, p.z, __int_as_float(n));
}

// ---------------------------------------------------------------- K5: grid KNN query
// 16-lane teams, one query each (cell-sorted order).  Per shell r the
// row-segments are enumerated in closed form: entry eid = 2*rid + side,
// rid -> (dz,dy) in the (2r+1)^2 row box; boundary rows (|dz|==r or
// |dy|==r) use side 0 = full clamped x-range; interior rows use side
// 0/1 = single cells cx-r / cx+r.  Rounds of 16 entries: each lane loads
// its own entry's (s0,s1) -- 16 independent L2 chains in flight (R7 had 1,
// R8's per-lane scan had 1/8 lane efficiency) -- then each segment is
// shfl-broadcast and scanned by ALL 16 lanes stride-16.  Exact top-16 via
// (d2,idx)-lexicographic u64 keys (validated R1-R8 formula).  Stop when
// team-min of per-lane 16th-bests <= (r*s)^2 - eps (Chebyshev bound).
#define SCANSEG(S0, S1)                                                      \
  for (int j = (S0) + l; j < (S1); j += 16) {                                \
    float4 A = sp[j];                                                        \
    float sqj = fmaf(A.z, A.z, fmaf(A.y, A.y, A.x * A.x));                   \
    float dot = q.x * A.x;                                                   \
    dot = fmaf(q.y, A.y, dot);                                               \
    dot = fmaf(q.z, A.z, dot);                                               \
    float d2 = (qsq + sqj) - 2.0f * dot;                                     \
    unsigned u = __float_as_uint(d2);                                        \
    u ^= (0x80000000u | (unsigned)((int)u >> 31));                           \
    u64 key = ((u64)u << 32) | (unsigned)__float_as_int(A.w);                \
    if (key < lst[15]) {                                                     \
      u64 x = key;                                                           \
      _Pragma("unroll") for (int p = 0; p < 16; ++p) {                       \
        bool sw = x < lst[p];                                                \
        u64 a = lst[p];                                                      \
        lst[p] = sw ? x : a;                                                 \
        x = sw ? a : x;                                                      \
      }                                                                      \
    }                                                                        \
  }

__global__ __launch_bounds__(256) void k_query(const float4* __restrict__ spts,
                                               const int* __restrict__ offs,
                                               const int* __restrict__ ends,
                                               const float* __restrict__ gp,
                                               u16* __restrict__ oidx) {
  __shared__ u64 kb[16 * 256];  // 32 KB merge keys: kb[(slot<<8) + tid]
  const int tid = threadIdx.x;
  const int l = tid & 15;       // team lane
  const int team = tid >> 4;    // 0..15 (query within block)
  const int lane = tid & 63;    // wave lane (teams are 16-aligned in wave)
  const int qid = blockIdx.x * 16 + team;
  const int b = qid >> 13, i = qid & 8191;
  const float4* __restrict__ sp = spts + (b << 13);
  const int* __restrict__ ob = offs + b * NCELL;
  const int* __restrict__ eb = ends + b * NCELL;
  const float* g = gp + b * 8;
  float4 q = sp[i];
  const float qsq = fmaf(q.z, q.z, fmaf(q.y, q.y, q.x * q.x));
  const int orig = __float_as_int(q.w);
  const int cx = cellof(q.x, g[0], g[4]);
  const int cy = cellof(q.y, g[1], g[4]);
  const int cz = cellof(q.z, g[2], g[4]);
  const float s = g[3];

  u64 lst[16];
#pragma unroll
  for (int p = 0; p < 16; ++p) lst[p] = ~0ULL;

  for (int r = 0; r <= GRID; ++r) {
    const int W = 2 * r + 1;
    const int nent = 2 * W * W;
    for (int base = 0; base < nent; base += 16) {
      // phase A: each lane loads bounds of its own entry (parallel chains)
      int ms0 = 0, ms1 = 0;
      const int eid = base + l;
      if (eid < nent) {
        const int rid = eid >> 1, side = eid & 1;
        const int dz = rid / W - r;
        const int dy = rid % W - r;
        const int z2 = cz + dz, y2 = cy + dy;
        if ((unsigned)z2 < GRID && (unsigned)y2 < GRID) {
          const int rowb = (z2 * GRID + y2) * GRID;
          const bool bdry = (dz == -r) || (dz == r) || (dy == -r) || (dy == r);
          if (bdry) {
            if (side == 0) {
              const int xl = cx - r < 0 ? 0 : cx - r;
              const int xh = cx + r > GRID - 1 ? GRID - 1 : cx + r;
              ms0 = ob[rowb + xl];
              ms1 = eb[rowb + xh];
            }
          } else {
            const int x2 = side ? cx + r : cx - r;
            if ((unsigned)x2 < GRID) {
              ms0 = ob[rowb + x2];
              ms1 = eb[rowb + x2];
            }
          }
        }
      }
      // phase B: broadcast each segment, scan with all 16 lanes
      const int tb = lane & 48;  // team base within wave
#pragma unroll 4
      for (int e = 0; e < 16; ++e) {
        const int s0 = __shfl(ms0, tb + e);
        const int s1 = __shfl(ms1, tb + e);
        if (s1 > s0) SCANSEG(s0, s1)
      }
    }
    // team stop check (xor 1,2,4,8 stays within 16-aligned team)
    float worst;
    if (lst[15] == ~0ULL) {
      worst = INFINITY;
    } else {
      unsigned v = (unsigned)(lst[15] >> 32);
      unsigned uo = (v & 0x80000000u) ? (v ^ 0x80000000u) : ~v;
      worst = __uint_as_float(uo);
    }
    worst = fminf(worst, __shfl_xor(worst, 1));
    worst = fminf(worst, __shfl_xor(worst, 2));
    worst = fminf(worst, __shfl_xor(worst, 4));
    worst = fminf(worst, __shfl_xor(worst, 8));
    const float rs = (float)r * s;
    if (worst <= fmaf(rs, rs, -1e-4f)) break;
  }

  // ---- merge 16 sorted lists per query (4 stages) ----
#pragma unroll
  for (int p = 0; p < 16; ++p) kb[(p << 8) + tid] = lst[p];
  __syncthreads();

  const int cbase = team << 4;
  u64 rb[16];
#pragma unroll
  for (int st = 0; st < 3; ++st) {
    const int stride = 1 << st;        // 1, 2, 4
    const int nm = 8 >> st;            // 8, 4, 2 merges
    const bool act = (l < nm);
    if (act) {
      const int la = cbase + (2 * l) * stride;
      const int lb = la + stride;
      int pa = 0, pb = 0;
      u64 ka = kb[la], kv = kb[lb];
#pragma unroll
      for (int k = 0; k < 16; ++k) {
        bool ta = ka < kv;
        rb[k] = ta ? ka : kv;
        if (ta) {
          ++pa;
          ka = (pa < 16) ? kb[(pa << 8) + la] : ~0ULL;
        } else {
          ++pb;
          kv = (pb < 16) ? kb[(pb << 8) + lb] : ~0ULL;
        }
      }
    }
    __syncthreads();
    if (act) {
      const int la = cbase + (2 * l) * (1 << st);
#pragma unroll
      for (int p = 0; p < 16; ++p) kb[(p << 8) + la] = rb[p];
    }
    __syncthreads();
  }
  if (l == 0) {  // final: merge (cbase, cbase+8) -> output
    const int la = cbase, lb = cbase + 8;
    int pa = 0, pb = 0;
    u64 ka = kb[la], kv = kb[lb];
    unsigned pk[8];
#pragma unroll
    for (int k = 0; k < 16; ++k) {
      bool ta = ka < kv;
      u64 sel = ta ? ka : kv;
      unsigned id16 = (unsigned)(sel & 0xFFFFull);
      if (k & 1)
        pk[k >> 1] |= id16 << 16;
      else
        pk[k >> 1] = id16;
      if (ta) {
        ++pa;
        ka = (pa < 16) ? kb[(pa << 8) + la] : ~0ULL;
      } else {
        ++pb;
        kv = (pb < 16) ? kb[(pb << 8) + lb] : ~0ULL;
      }
    }
    unsigned* od = (unsigned*)(oidx + (((size_t)(b << 13) + orig) << 4));
#pragma unroll
    for (int k = 0; k < 8; ++k) od[k] = pk[k];
  }
}

// ---------------------------------------------------------------- K6: lt = feat @ lt_w + lt_b
__global__ __launch_bounds__(256) void k_lt(const float* __restrict__ feat,
                                            const float* __restrict__ ltw,
                                            const float* __restrict__ ltb,
                                            float* __restrict__ lt) {
  __shared__ float sw[64][196];
  __shared__ float sf[32][68];
  const int tid = threadIdx.x;
  const int r0 = blockIdx.x * 32;
#pragma unroll
  for (int i = 0; i < 12; ++i) {
    int v = tid + i * 256;
    float4 w4 = ((const float4*)ltw)[v];
    int row = (v * 4) / 192, col = (v * 4) % 192;
    *(float4*)&sw[row][col] = w4;
  }
#pragma unroll
  for (int i = 0; i < 2; ++i) {
    int v = tid + i * 256;
    int row = v >> 4, c4 = v & 15;
    float4 f4 = ((const float4*)(feat + (size_t)(r0 + row) * 64))[c4];
    *(float4*)&sf[row][c4 * 4] = f4;
  }
  __syncthreads();
  const int r = tid >> 3;
  const int c0 = (tid & 7) * 24;
  float acc[24];
#pragma unroll
  for (int ll = 0; ll < 24; ++ll) acc[ll] = ltb[c0 + ll];
#pragma unroll 4
  for (int j = 0; j < 64; ++j) {
    float f = sf[r][j];
#pragma unroll
    for (int l4 = 0; l4 < 6; ++l4) {
      float4 w4 = *(const float4*)&sw[j][c0 + l4 * 4];
      acc[l4 * 4 + 0] = fmaf(f, w4.x, acc[l4 * 4 + 0]);
      acc[l4 * 4 + 1] = fmaf(f, w4.y, acc[l4 * 4 + 1]);
      acc[l4 * 4 + 2] = fmaf(f, w4.z, acc[l4 * 4 + 2]);
      acc[l4 * 4 + 3] = fmaf(f, w4.w, acc[l4 * 4 + 3]);
    }
  }
  float* orow = lt + (size_t)(r0 + r) * 192 + c0;
#pragma unroll
  for (int l4 = 0; l4 < 6; ++l4)
    *(float4*)&orow[l4 * 4] = make_float4(acc[l4 * 4], acc[l4 * 4 + 1],
                                          acc[l4 * 4 + 2], acc[l4 * 4 + 3]);
}

// ---------------------------------------------------------------- K7: main
__global__ __launch_bounds__(256) void k_main(
    const float4* __restrict__ xytp, const float* __restrict__ lt,
    const u16* __restrict__ knn, const float* __restrict__ pe_w1,
    const float* __restrict__ pe_b1, const float* __restrict__ pe_w2,
    const float* __restrict__ pe_b2, const float* __restrict__ ln_g,
    const float* __restrict__ ln_b, float* __restrict__ out) {
  __shared__ float s_h[4][16][64];
  const int lane = threadIdx.x & 63;
  const int wave = threadIdx.x >> 6;
  const int pid = __builtin_amdgcn_readfirstlane(blockIdx.x * 4 + wave);
  const int b = pid >> 13;
  const int n = pid & 8191;

  float w1c[4];
#pragma unroll
  for (int d = 0; d < 4; ++d) w1c[d] = pe_w1[d * 64 + lane];
  const float b1c = pe_b1[lane];
  float w2c[64];
#pragma unroll
  for (int j = 0; j < 64; ++j) w2c[j] = pe_w2[j * 64 + lane];
  const float b2c = pe_b2[lane];
  const float gc = ln_g[lane], bc = ln_b[lane];

  int nb[16];
#pragma unroll
  for (int k = 0; k < 16; ++k) nb[k] = knn[pid * 16 + k];

  const float* __restrict__ ltb = lt + (size_t)(b << 13) * 192;
  float psi[16], alp[16];
#pragma unroll
  for (int k = 0; k < 16; ++k) {
    const float* row = ltb + (size_t)nb[k] * 192;
    psi[k] = row[64 + lane];
    alp[k] = row[128 + lane];
  }
  const float vc = ltb[(size_t)n * 192 + lane];

  const float4 qv = xytp[(b << 13) + n];
#pragma unroll
  for (int k = 0; k < 16; ++k) {
    float4 g = xytp[(b << 13) + nb[k]];
    float r0 = qv.x - g.x, r1 = qv.y - g.y, r2 = qv.z - g.z, r3 = qv.w - g.w;
    float h = fmaf(r3, w1c[3],
                   fmaf(r2, w1c[2], fmaf(r1, w1c[1], fmaf(r0, w1c[0], b1c))));
    s_h[wave][k][lane] = fmaxf(h, 0.0f);
  }
  __syncthreads();

  float pre[16], apd[16];
#pragma unroll
  for (int k = 0; k < 16; ++k) {
    float acc = b2c;
#pragma unroll
    for (int j4 = 0; j4 < 16; ++j4) {
      float4 h4 = *(const float4*)&s_h[wave][k][j4 * 4];
      acc = fmaf(h4.x, w2c[j4 * 4 + 0], acc);
      acc = fmaf(h4.y, w2c[j4 * 4 + 1], acc);
      acc = fmaf(h4.z, w2c[j4 * 4 + 2], acc);
      acc = fmaf(h4.w, w2c[j4 * 4 + 3], acc);
    }
    pre[k] = (vc - psi[k]) + acc;
    apd[k] = alp[k] + acc;
  }

  float xk[16], m = -INFINITY;
#pragma unroll
  for (int k = 0; k < 16; ++k) {
    float s = pre[k], ss = pre[k] * pre[k];
#pragma unroll
    for (int d = 1; d < 64; d <<= 1) {
      s += __shfl_xor(s, d);
      ss += __shfl_xor(ss, d);
    }
    float mu = s * 0.015625f;
    float var = fmaf(ss, 0.015625f, -mu * mu);
    float inv = 1.0f / sqrtf(var + 1e-5f);
    float lnv = fmaf((pre[k] - mu) * inv, gc, bc);
    xk[k] = lnv * 0.125f;
    m = fmaxf(m, xk[k]);
  }
  float se = 0.f, acc = 0.f;
#pragma unroll
  for (int k = 0; k < 16; ++k) {
    float e = __expf(xk[k] - m);
    se += e;
    acc = fmaf(e, apd[k], acc);
  }
  out[(size_t)pid * 64 + lane] = acc / se;
}

// ---------------------------------------------------------------- launch
extern "C" void kernel_launch(void* const* d_in, const int* in_sizes, int n_in,
                              void* d_out, int out_size, void* d_ws,
                              size_t ws_size, hipStream_t stream) {
  const float4* xytp = (const float4*)d_in[0];
  const float* features = (const float*)d_in[1];
  const float* pe_w1 = (const float*)d_in[2];
  const float* pe_b1 = (const float*)d_in[3];
  const float* pe_w2 = (const float*)d_in[4];
  const float* pe_b2 = (const float*)d_in[5];
  const float* lt_w = (const float*)d_in[6];
  const float* lt_b = (const float*)d_in[7];
  const float* ln_g = (const float*)d_in[8];
  const float* ln_b = (const float*)d_in[9];
  float* out = (float*)d_out;

  char* ws = (char*)d_ws;
  u16* idxbuf = (u16*)(ws + WS_IDX);
  float* lt = (float*)(ws + WS_LT);
  int* cnt = (int*)(ws + WS_CNT);
  int* offs = (int*)(ws + WS_OFF);
  int* curs = (int*)(ws + WS_CUR);
  float4* spts = (float4*)(ws + WS_SP);
  float* gp = (float*)(ws + WS_GP);

  k_minmax<<<BATCH, 256, 0, stream>>>(xytp, gp, cnt);
  k_count<<<(BATCH * NPTS) / 256, 256, 0, stream>>>(xytp, gp, cnt);
  k_scan<<<BATCH, 1024, 0, stream>>>(cnt, offs, curs);
  k_scatter<<<(BATCH * NPTS) / 256, 256, 0, stream>>>(xytp, gp, curs, spts);
  k_query<<<(BATCH * NPTS) / 16, 256, 0, stream>>>(spts, offs, curs, gp,
                                                   idxbuf);
  k_lt<<<(BATCH * NPTS) / 32, 256, 0, stream>>>(features, lt_w, lt_b, lt);
  k_main<<<(BATCH * NPTS) / 4, 256, 0, stream>>>(xytp, lt, idxbuf, pe_w1,
                                                 pe_b1, pe_w2, pe_b2, ln_g,
                                                 ln_b, out);
}

// Round 10
// 558.854 us; speedup vs baseline: 2.6310x; 1.1747x over previous
//
#include <hip/hip_runtime.h>
#include <stdint.h>

#define BATCH 4
#define NPTS 8192
#define KNN_K 16
#define GRID 24
#define NCELL (GRID * GRID * GRID)  // 13824
#define NCELLP (NCELL + 8)          // offs stride (sentinel slot)

typedef unsigned long long u64;
typedef unsigned short u16;

// ws layout (bytes)
#define WS_IDX 0u          // u16[4*8192*16]            = 1,048,576
#define WS_LT 1048576u     // float[4*8192*192]         = 25,165,824
#define WS_CNT 26214400u   // int[4*13824]              = 221,184
#define WS_OFF 26435584u   // int[4*13832]              = 221,312
#define WS_CUR 26656896u   // int[4*13824]              = 221,184
#define WS_SP 26878080u    // float4[4*8192]            = 524,288
#define WS_GP 27402368u    // float[4*8]                = 128
#define WS_SIDX 27402496u  // u16[4*8192]               = 65,536

__device__ __forceinline__ int cellof(float v, float o, float invs) {
  int c = (int)((v - o) * invs);
  return c < GRID - 1 ? c : GRID - 1;
}

// ---------------------------------------------------------------- K0: bbox + zero counters
__global__ __launch_bounds__(256) void k_minmax(const float4* __restrict__ xytp,
                                                float* __restrict__ gp,
                                                int* __restrict__ cnt) {
  const int b = blockIdx.x, t = threadIdx.x;
  for (int c = t; c < NCELL; c += 256) cnt[b * NCELL + c] = 0;
  const float4* pb = xytp + (b << 13);
  float mnx = INFINITY, mny = INFINITY, mnz = INFINITY;
  float mxx = -INFINITY, mxy = -INFINITY, mxz = -INFINITY;
  for (int i = t; i < NPTS; i += 256) {
    float4 p = pb[i];
    mnx = fminf(mnx, p.x); mny = fminf(mny, p.y); mnz = fminf(mnz, p.z);
    mxx = fmaxf(mxx, p.x); mxy = fmaxf(mxy, p.y); mxz = fmaxf(mxz, p.z);
  }
#pragma unroll
  for (int d = 1; d < 64; d <<= 1) {
    mnx = fminf(mnx, __shfl_xor(mnx, d)); mny = fminf(mny, __shfl_xor(mny, d));
    mnz = fminf(mnz, __shfl_xor(mnz, d)); mxx = fmaxf(mxx, __shfl_xor(mxx, d));
    mxy = fmaxf(mxy, __shfl_xor(mxy, d)); mxz = fmaxf(mxz, __shfl_xor(mxz, d));
  }
  __shared__ float red[4][6];
  const int lane = t & 63, wv = t >> 6;
  if (lane == 0) {
    red[wv][0] = mnx; red[wv][1] = mny; red[wv][2] = mnz;
    red[wv][3] = mxx; red[wv][4] = mxy; red[wv][5] = mxz;
  }
  __syncthreads();
  if (t == 0) {
    for (int w = 1; w < 4; ++w) {
      red[0][0] = fminf(red[0][0], red[w][0]);
      red[0][1] = fminf(red[0][1], red[w][1]);
      red[0][2] = fminf(red[0][2], red[w][2]);
      red[0][3] = fmaxf(red[0][3], red[w][3]);
      red[0][4] = fmaxf(red[0][4], red[w][4]);
      red[0][5] = fmaxf(red[0][5], red[w][5]);
    }
    float rmax = fmaxf(red[0][3] - red[0][0],
                       fmaxf(red[0][4] - red[0][1], red[0][5] - red[0][2]));
    float s = rmax / (float)GRID;
    float* g = gp + b * 8;
    g[0] = red[0][0]; g[1] = red[0][1]; g[2] = red[0][2];
    g[3] = s; g[4] = 1.0f / s;
  }
}

// ---------------------------------------------------------------- K2: count
__global__ __launch_bounds__(256) void k_count(const float4* __restrict__ xytp,
                                               const float* __restrict__ gp,
                                               int* __restrict__ cnt) {
  int i = blockIdx.x * 256 + threadIdx.x;
  int b = i >> 13;
  const float* g = gp + b * 8;
  float4 p = xytp[i];
  int cx = cellof(p.x, g[0], g[4]);
  int cy = cellof(p.y, g[1], g[4]);
  int cz = cellof(p.z, g[2], g[4]);
  atomicAdd(&cnt[b * NCELL + (cz * GRID + cy) * GRID + cx], 1);
}

// ---------------------------------------------------------------- K3: exclusive scan
// offs has stride NCELLP with offs[b*NCELLP + NCELL] = NPTS sentinel, so
// end(cell c) == offs[c+1] works for every cell including the last.
__global__ __launch_bounds__(1024) void k_scan(const int* __restrict__ cnt,
                                               int* __restrict__ offs,
                                               int* __restrict__ curs) {
  __shared__ int wsum[16];
  const int b = blockIdx.x, t = threadIdx.x;
  const int base = b * NCELL;
  const int base2 = b * NCELLP;
  const int lo = t * 14;
  const int hi = lo + 14 < NCELL ? lo + 14 : NCELL;
  int s = 0;
  for (int c = lo; c < hi; ++c) s += cnt[base + c];
  const int lane = t & 63, wv = t >> 6;
  int v = s;
#pragma unroll
  for (int d = 1; d < 64; d <<= 1) {
    int u = __shfl_up(v, d);
    if (lane >= d) v += u;
  }
  if (lane == 63) wsum[wv] = v;
  __syncthreads();
  if (wv == 0 && lane < 16) {
    int x = wsum[lane];
#pragma unroll
    for (int d = 1; d < 16; d <<= 1) {
      int u = __shfl_up(x, d, 16);
      if (lane >= d) x += u;
    }
    wsum[lane] = x;
  }
  __syncthreads();
  int excl = (wv > 0 ? wsum[wv - 1] : 0) + v - s;
  for (int c = lo; c < hi; ++c) {
    offs[base2 + c] = excl;
    curs[base + c] = excl;
    excl += cnt[base + c];
  }
  if (hi == NCELL) offs[base2 + NCELL] = excl;  // == NPTS
}

// ---------------------------------------------------------------- K4: scatter (cell-sorted points, sq in .w, idx in sidx)
__global__ __launch_bounds__(256) void k_scatter(const float4* __restrict__ xytp,
                                                 const float* __restrict__ gp,
                                                 int* __restrict__ curs,
                                                 float4* __restrict__ spts,
                                                 u16* __restrict__ sidx) {
  int i = blockIdx.x * 256 + threadIdx.x;
  int b = i >> 13, n = i & 8191;
  const float* g = gp + b * 8;
  float4 p = xytp[i];
  int cx = cellof(p.x, g[0], g[4]);
  int cy = cellof(p.y, g[1], g[4]);
  int cz = cellof(p.z, g[2], g[4]);
  int pos = atomicAdd(&curs[b * NCELL + (cz * GRID + cy) * GRID + cx], 1);
  float sq = fmaf(p.z, p.z, fmaf(p.y, p.y, p.x * p.x));
  spts[(b << 13) + pos] = make_float4(p.x, p.y, p.z, sq);
  sidx[(b << 13) + pos] = (u16)n;
}

// ---------------------------------------------------------------- K5: grid KNN query
// 128-thr blocks (8 teams of 16 lanes, one query each, cell-sorted order).
// Shell entries enumerated in closed form (boundary rows = full x-range,
// interior rows = singles at cx±r).  Phase A: each lane loads its own
// entry bounds (16 parallel L2 chains; end = offs[c+1] via sentinel).
// Phase B: ballot-compacted — only NON-EMPTY segments are broadcast and
// scanned by all 16 lanes stride-16 (R9 burned 16 iterations regardless).
// Exact top-16 per lane via (d2, orig-idx)-lexicographic u64 keys
// (validated R1-R9); sq precomputed in spts.w; orig idx from sidx.
// Stop: team-min of lane 16th-bests <= (r*s)^2 - eps (Chebyshev bound).
#define SCANSEG(S0, S1)                                                      \
  for (int j = (S0) + l; j < (S1); j += 16) {                                \
    float4 A = sp[j];                                                        \
    unsigned oi = sx[j];                                                     \
    float dot = q.x * A.x;                                                   \
    dot = fmaf(q.y, A.y, dot);                                               \
    dot = fmaf(q.z, A.z, dot);                                               \
    float d2 = (qsq + A.w) - 2.0f * dot;                                     \
    unsigned u = __float_as_uint(d2);                                        \
    u ^= (0x80000000u | (unsigned)((int)u >> 31));                           \
    u64 key = ((u64)u << 32) | oi;                                           \
    if (key < lst[15]) {                                                     \
      u64 x = key;                                                           \
      _Pragma("unroll") for (int p = 0; p < 16; ++p) {                       \
        bool sw = x < lst[p];                                                \
        u64 a = lst[p];                                                      \
        lst[p] = sw ? x : a;                                                 \
        x = sw ? a : x;                                                      \
      }                                                                      \
    }                                                                        \
  }

__global__ __launch_bounds__(128) void k_query(const float4* __restrict__ spts,
                                               const u16* __restrict__ sidx,
                                               const int* __restrict__ offs,
                                               const float* __restrict__ gp,
                                               u16* __restrict__ oidx) {
  __shared__ u64 kb[16 * 128];  // 16 KB merge keys: kb[(slot<<7) + tid]
  const int tid = threadIdx.x;
  const int l = tid & 15;       // team lane
  const int team = tid >> 4;    // 0..7 (query within block)
  const int lane = tid & 63;    // wave lane
  const int qid = blockIdx.x * 8 + team;
  const int b = qid >> 13, i = qid & 8191;
  const float4* __restrict__ sp = spts + (b << 13);
  const u16* __restrict__ sx = sidx + (b << 13);
  const int* __restrict__ ob = offs + b * NCELLP;
  const float* g = gp + b * 8;
  float4 q = sp[i];
  const float qsq = q.w;  // sq precomputed
  const unsigned orig = sx[i];
  const int cx = cellof(q.x, g[0], g[4]);
  const int cy = cellof(q.y, g[1], g[4]);
  const int cz = cellof(q.z, g[2], g[4]);
  const float s = g[3];

  u64 lst[16];
#pragma unroll
  for (int p = 0; p < 16; ++p) lst[p] = ~0ULL;

  const int tb = lane & 48;  // team base within wave

  for (int r = 0; r <= GRID; ++r) {
    const int W = 2 * r + 1;
    const int nent = 2 * W * W;
    for (int base = 0; base < nent; base += 16) {
      // phase A: each lane loads bounds of its own entry (parallel chains)
      int ms0 = 0, ms1 = 0;
      const int eid = base + l;
      if (eid < nent) {
        const int rid = eid >> 1, side = eid & 1;
        const int dz = rid / W - r;
        const int dy = rid % W - r;
        const int z2 = cz + dz, y2 = cy + dy;
        if ((unsigned)z2 < GRID && (unsigned)y2 < GRID) {
          const int rowb = (z2 * GRID + y2) * GRID;
          const bool bdry = (dz == -r) || (dz == r) || (dy == -r) || (dy == r);
          if (bdry) {
            if (side == 0) {
              const int xl = cx - r < 0 ? 0 : cx - r;
              const int xh = cx + r > GRID - 1 ? GRID - 1 : cx + r;
              ms0 = ob[rowb + xl];
              ms1 = ob[rowb + xh + 1];
            }
          } else {
            const int x2 = side ? cx + r : cx - r;
            if ((unsigned)x2 < GRID) {
              ms0 = ob[rowb + x2];
              ms1 = ob[rowb + x2 + 1];
            }
          }
        }
      }
      // phase B: ballot-compact non-empty segments, broadcast, scan
      unsigned m = (unsigned)((__ballot(ms1 > ms0) >> tb) & 0xFFFFull);
      while (m) {
        const int e = __ffs(m) - 1;
        m &= m - 1;
        const int s0 = __shfl(ms0, tb + e);
        const int s1 = __shfl(ms1, tb + e);
        SCANSEG(s0, s1)
      }
    }
    // team stop check (xor 1,2,4,8 stays within 16-aligned team)
    float worst;
    if (lst[15] == ~0ULL) {
      worst = INFINITY;
    } else {
      unsigned v = (unsigned)(lst[15] >> 32);
      unsigned uo = (v & 0x80000000u) ? (v ^ 0x80000000u) : ~v;
      worst = __uint_as_float(uo);
    }
    worst = fminf(worst, __shfl_xor(worst, 1));
    worst = fminf(worst, __shfl_xor(worst, 2));
    worst = fminf(worst, __shfl_xor(worst, 4));
    worst = fminf(worst, __shfl_xor(worst, 8));
    const float rs = (float)r * s;
    if (worst <= fmaf(rs, rs, -1e-4f)) break;
  }

  // ---- merge 16 sorted lists per query (4 stages) ----
#pragma unroll
  for (int p = 0; p < 16; ++p) kb[(p << 7) + tid] = lst[p];
  __syncthreads();

  const int cbase = team << 4;
  u64 rb[16];
#pragma unroll
  for (int st = 0; st < 3; ++st) {
    const int stride = 1 << st;        // 1, 2, 4
    const int nm = 8 >> st;            // 8, 4, 2 merges
    const bool act = (l < nm);
    if (act) {
      const int la = cbase + (2 * l) * stride;
      const int lb = la + stride;
      int pa = 0, pb = 0;
      u64 ka = kb[la], kv = kb[lb];
#pragma unroll
      for (int k = 0; k < 16; ++k) {
        bool ta = ka < kv;
        rb[k] = ta ? ka : kv;
        if (ta) {
          ++pa;
          ka = (pa < 16) ? kb[(pa << 7) + la] : ~0ULL;
        } else {
          ++pb;
          kv = (pb < 16) ? kb[(pb << 7) + lb] : ~0ULL;
        }
      }
    }
    __syncthreads();
    if (act) {
      const int la = cbase + (2 * l) * (1 << st);
#pragma unroll
      for (int p = 0; p < 16; ++p) kb[(p << 7) + la] = rb[p];
    }
    __syncthreads();
  }
  if (l == 0) {  // final: merge (cbase, cbase+8) -> output
    const int la = cbase, lb = cbase + 8;
    int pa = 0, pb = 0;
    u64 ka = kb[la], kv = kb[lb];
    unsigned pk[8];
#pragma unroll
    for (int k = 0; k < 16; ++k) {
      bool ta = ka < kv;
      u64 sel = ta ? ka : kv;
      unsigned id16 = (unsigned)(sel & 0xFFFFull);
      if (k & 1)
        pk[k >> 1] |= id16 << 16;
      else
        pk[k >> 1] = id16;
      if (ta) {
        ++pa;
        ka = (pa < 16) ? kb[(pa << 7) + la] : ~0ULL;
      } else {
        ++pb;
        kv = (pb < 16) ? kb[(pb << 7) + lb] : ~0ULL;
      }
    }
    unsigned* od = (unsigned*)(oidx + (((size_t)(b << 13) + orig) << 4));
#pragma unroll
    for (int k = 0; k < 8; ++k) od[k] = pk[k];
  }
}

// ---------------------------------------------------------------- K6: lt = feat @ lt_w + lt_b
__global__ __launch_bounds__(256) void k_lt(const float* __restrict__ feat,
                                            const float* __restrict__ ltw,
                                            const float* __restrict__ ltb,
                                            float* __restrict__ lt) {
  __shared__ float sw[64][196];
  __shared__ float sf[32][68];
  const int tid = threadIdx.x;
  const int r0 = blockIdx.x * 32;
#pragma unroll
  for (int i = 0; i < 12; ++i) {
    int v = tid + i * 256;
    float4 w4 = ((const float4*)ltw)[v];
    int row = (v * 4) / 192, col = (v * 4) % 192;
    *(float4*)&sw[row][col] = w4;
  }
#pragma unroll
  for (int i = 0; i < 2; ++i) {
    int v = tid + i * 256;
    int row = v >> 4, c4 = v & 15;
    float4 f4 = ((const float4*)(feat + (size_t)(r0 + row) * 64))[c4];
    *(float4*)&sf[row][c4 * 4] = f4;
  }
  __syncthreads();
  const int r = tid >> 3;
  const int c0 = (tid & 7) * 24;
  float acc[24];
#pragma unroll
  for (int ll = 0; ll < 24; ++ll) acc[ll] = ltb[c0 + ll];
#pragma unroll 4
  for (int j = 0; j < 64; ++j) {
    float f = sf[r][j];
#pragma unroll
    for (int l4 = 0; l4 < 6; ++l4) {
      float4 w4 = *(const float4*)&sw[j][c0 + l4 * 4];
      acc[l4 * 4 + 0] = fmaf(f, w4.x, acc[l4 * 4 + 0]);
      acc[l4 * 4 + 1] = fmaf(f, w4.y, acc[l4 * 4 + 1]);
      acc[l4 * 4 + 2] = fmaf(f, w4.z, acc[l4 * 4 + 2]);
      acc[l4 * 4 + 3] = fmaf(f, w4.w, acc[l4 * 4 + 3]);
    }
  }
  float* orow = lt + (size_t)(r0 + r) * 192 + c0;
#pragma unroll
  for (int l4 = 0; l4 < 6; ++l4)
    *(float4*)&orow[l4 * 4] = make_float4(acc[l4 * 4], acc[l4 * 4 + 1],
                                          acc[l4 * 4 + 2], acc[l4 * 4 + 3]);
}

// ---------------------------------------------------------------- K7: main
__global__ __launch_bounds__(256) void k_main(
    const float4* __restrict__ xytp, const float* __restrict__ lt,
    const u16* __restrict__ knn, const float* __restrict__ pe_w1,
    const float* __restrict__ pe_b1, const float* __restrict__ pe_w2,
    const float* __restrict__ pe_b2, const float* __restrict__ ln_g,
    const float* __restrict__ ln_b, float* __restrict__ out) {
  __shared__ float s_h[4][16][64];
  const int lane = threadIdx.x & 63;
  const int wave = threadIdx.x >> 6;
  const int pid = __builtin_amdgcn_readfirstlane(blockIdx.x * 4 + wave);
  const int b = pid >> 13;
  const int n = pid & 8191;

  float w1c[4];
#pragma unroll
  for (int d = 0; d < 4; ++d) w1c[d] = pe_w1[d * 64 + lane];
  const float b1c = pe_b1[lane];
  float w2c[64];
#pragma unroll
  for (int j = 0; j < 64; ++j) w2c[j] = pe_w2[j * 64 + lane];
  const float b2c = pe_b2[lane];
  const float gc = ln_g[lane], bc = ln_b[lane];

  int nb[16];
#pragma unroll
  for (int k = 0; k < 16; ++k) nb[k] = knn[pid * 16 + k];

  const float* __restrict__ ltb = lt + (size_t)(b << 13) * 192;
  float psi[16], alp[16];
#pragma unroll
  for (int k = 0; k < 16; ++k) {
    const float* row = ltb + (size_t)nb[k] * 192;
    psi[k] = row[64 + lane];
    alp[k] = row[128 + lane];
  }
  const float vc = ltb[(size_t)n * 192 + lane];

  const float4 qv = xytp[(b << 13) + n];
#pragma unroll
  for (int k = 0; k < 16; ++k) {
    float4 g = xytp[(b << 13) + nb[k]];
    float r0 = qv.x - g.x, r1 = qv.y - g.y, r2 = qv.z - g.z, r3 = qv.w - g.w;
    float h = fmaf(r3, w1c[3],
                   fmaf(r2, w1c[2], fmaf(r1, w1c[1], fmaf(r0, w1c[0], b1c))));
    s_h[wave][k][lane] = fmaxf(h, 0.0f);
  }
  __syncthreads();

  float pre[16], apd[16];
#pragma unroll
  for (int k = 0; k < 16; ++k) {
    float acc = b2c;
#pragma unroll
    for (int j4 = 0; j4 < 16; ++j4) {
      float4 h4 = *(const float4*)&s_h[wave][k][j4 * 4];
      acc = fmaf(h4.x, w2c[j4 * 4 + 0], acc);
      acc = fmaf(h4.y, w2c[j4 * 4 + 1], acc);
      acc = fmaf(h4.z, w2c[j4 * 4 + 2], acc);
      acc = fmaf(h4.w, w2c[j4 * 4 + 3], acc);
    }
    pre[k] = (vc - psi[k]) + acc;
    apd[k] = alp[k] + acc;
  }

  float xk[16], m = -INFINITY;
#pragma unroll
  for (int k = 0; k < 16; ++k) {
    float s = pre[k], ss = pre[k] * pre[k];
#pragma unroll
    for (int d = 1; d < 64; d <<= 1) {
      s += __shfl_xor(s, d);
      ss += __shfl_xor(ss, d);
    }
    float mu = s * 0.015625f;
    float var = fmaf(ss, 0.015625f, -mu * mu);
    float inv = 1.0f / sqrtf(var + 1e-5f);
    float lnv = fmaf((pre[k] - mu) * inv, gc, bc);
    xk[k] = lnv * 0.125f;
    m = fmaxf(m, xk[k]);
  }
  float se = 0.f, acc = 0.f;
#pragma unroll
  for (int k = 0; k < 16; ++k) {
    float e = __expf(xk[k] - m);
    se += e;
    acc = fmaf(e, apd[k], acc);
  }
  out[(size_t)pid * 64 + lane] = acc / se;
}

// ---------------------------------------------------------------- launch
extern "C" void kernel_launch(void* const* d_in, const int* in_sizes, int n_in,
                              void* d_out, int out_size, void* d_ws,
                              size_t ws_size, hipStream_t stream) {
  const float4* xytp = (const float4*)d_in[0];
  const float* features = (const float*)d_in[1];
  const float* pe_w1 = (const float*)d_in[2];
  const float* pe_b1 = (const float*)d_in[3];
  const float* pe_w2 = (const float*)d_in[4];
  const float* pe_b2 = (const float*)d_in[5];
  const float* lt_w = (const float*)d_in[6];
  const float* lt_b = (const float*)d_in[7];
  const float* ln_g = (const float*)d_in[8];
  const float* ln_b = (const float*)d_in[9];
  float* out = (float*)d_out;

  char* ws = (char*)d_ws;
  u16* idxbuf = (u16*)(ws + WS_IDX);
  float* lt = (float*)(ws + WS_LT);
  int* cnt = (int*)(ws + WS_CNT);
  int* offs = (int*)(ws + WS_OFF);
  int* curs = (int*)(ws + WS_CUR);
  float4* spts = (float4*)(ws + WS_SP);
  float* gp = (float*)(ws + WS_GP);
  u16* sidx = (u16*)(ws + WS_SIDX);

  k_minmax<<<BATCH, 256, 0, stream>>>(xytp, gp, cnt);
  k_count<<<(BATCH * NPTS) / 256, 256, 0, stream>>>(xytp, gp, cnt);
  k_scan<<<BATCH, 1024, 0, stream>>>(cnt, offs, curs);
  k_scatter<<<(BATCH * NPTS) / 256, 256, 0, stream>>>(xytp, gp, curs, spts,
                                                      sidx);
  k_query<<<(BATCH * NPTS) / 8, 128, 0, stream>>>(spts, sidx, offs, gp,
                                                  idxbuf);
  k_lt<<<(BATCH * NPTS) / 32, 256, 0, stream>>>(features, lt_w, lt_b, lt);
  k_main<<<(BATCH * NPTS) / 4, 256, 0, stream>>>(xytp, lt, idxbuf, pe_w1,
                                                 pe_b1, pe_w2, pe_b2, ln_g,
                                                 ln_b, out);
}